// Round 5
// baseline (497.500 us; speedup 1.0000x reference)
//
#include <hip/hip_runtime.h>
#include <math.h>

// GraphSAGE 2-layer + MLP head + softmax(2).
// Structure: CSR build, then per layer {GEMM (t=X@Wl bf16, r=X@Wr+b f32),
// AGG (h = sigmoid(mean(t[nbrs]) + r))}, then MLP head.
// Uses mean-aggregation linearity: mean(X[nbrs])@Wl == mean((X@Wl)[nbrs]).

#define NF1 48
#define HH 64

__global__ __launch_bounds__(256) void k_hist(const int* __restrict__ ei,
                                              int* __restrict__ hist, int E) {
  int e = blockIdx.x * 256 + threadIdx.x;
  if (e < E) atomicAdd(&hist[ei[E + e]], 1);
}

__global__ __launch_bounds__(256) void k_scan1(int* __restrict__ rp,
                                               int* __restrict__ bsum, int Nn) {
  __shared__ int a[256], b[256];
  int tid = threadIdx.x;
  int i = blockIdx.x * 256 + tid;
  int v = (i < Nn) ? rp[i] : 0;
  a[tid] = v;
  __syncthreads();
  int* s = a;
  int* d = b;
  for (int off = 1; off < 256; off <<= 1) {
    int t = s[tid] + ((tid >= off) ? s[tid - off] : 0);
    d[tid] = t;
    __syncthreads();
    int* tmp = s; s = d; d = tmp;
  }
  int incl = s[tid];
  if (i < Nn) rp[i] = incl - v;
  if (tid == 255) bsum[blockIdx.x] = incl;
}

// parallel single-block exclusive scan of block sums (nb <= 512)
__global__ __launch_bounds__(512) void k_scan2(int* __restrict__ bsum, int nb) {
  __shared__ int a[512], b[512];
  int tid = threadIdx.x;
  int v = (tid < nb) ? bsum[tid] : 0;
  a[tid] = v;
  __syncthreads();
  int* s = a;
  int* d = b;
  for (int off = 1; off < 512; off <<= 1) {
    int t = s[tid] + ((tid >= off) ? s[tid - off] : 0);
    d[tid] = t;
    __syncthreads();
    int* tmp = s; s = d; d = tmp;
  }
  if (tid < nb) bsum[tid] = s[tid] - v;
}

__global__ __launch_bounds__(256) void k_scan3(int* __restrict__ rp,
                                               int* __restrict__ cursor,
                                               const int* __restrict__ bsum,
                                               int Nn, int E) {
  int i = blockIdx.x * 256 + threadIdx.x;
  if (i < Nn) {
    int v = rp[i] + bsum[blockIdx.x];
    rp[i] = v;
    cursor[i] = v;
  }
  if (i == 0) rp[Nn] = E;
}

__global__ __launch_bounds__(256) void k_scatter(const int* __restrict__ ei,
                                                 int* __restrict__ cursor,
                                                 int* __restrict__ csr, int E) {
  int e = blockIdx.x * 256 + threadIdx.x;
  if (e >= E) return;
  int s = ei[e], d2 = ei[E + e];
  int idx = atomicAdd(&cursor[d2], 1);
  csr[idx] = s;
}

__device__ __forceinline__ float sigmoidf_(float v) {
  return 1.0f / (1.0f + __expf(-v));
}
__device__ __forceinline__ float bflo(unsigned w) {
  union { unsigned u; float f; } c; c.u = w << 16; return c.f;
}
__device__ __forceinline__ float bfhi(unsigned w) {
  union { unsigned u; float f; } c; c.u = w & 0xffff0000u; return c.f;
}
__device__ __forceinline__ unsigned short f2bf(float f) {
  union { float f; unsigned u; } c; c.f = f;
  unsigned r = c.u + 0x7fffu + ((c.u >> 16) & 1u);  // RNE
  return (unsigned short)(r >> 16);
}

// t_out[n] = X[n] @ Wl  (bf16), r_out[n] = X[n] @ Wr + bias  (f32)
template <int K>
__global__ __launch_bounds__(512) void gemm_tr(
    const float* __restrict__ X, const float* __restrict__ Wl,
    const float* __restrict__ Wr, const float* __restrict__ bias,
    unsigned short* __restrict__ t_out, float* __restrict__ r_out,
    int n_nodes) {
  __shared__ float sW[K * 128];   // [k][j]: j<64 -> Wl, j>=64 -> Wr
  __shared__ float sb[64];
  __shared__ float sx[8][K];
  for (int i = threadIdx.x; i < K * 64; i += 512) {
    int k = i >> 6, j = i & 63;
    sW[k * 128 + j] = Wl[i];
    sW[k * 128 + 64 + j] = Wr[i];
  }
  if (threadIdx.x < 64) sb[threadIdx.x] = bias[threadIdx.x];
  __syncthreads();

  int wv = threadIdx.x >> 6, lane = threadIdx.x & 63;
  for (int nbase = blockIdx.x * 8; nbase < n_nodes; nbase += gridDim.x * 8) {
    int node = nbase + wv;
    bool valid = node < n_nodes;
    int nn = valid ? node : (n_nodes - 1);
    if (lane < K) sx[wv][lane] = X[(size_t)nn * K + lane];
    __syncthreads();

    float acc_t = 0.0f, acc_r = sb[lane];
#pragma unroll
    for (int k = 0; k < K; k += 4) {
      float4 a = *(const float4*)&sx[wv][k];
      acc_t += a.x * sW[(k + 0) * 128 + lane] + a.y * sW[(k + 1) * 128 + lane] +
               a.z * sW[(k + 2) * 128 + lane] + a.w * sW[(k + 3) * 128 + lane];
      acc_r += a.x * sW[(k + 0) * 128 + 64 + lane] +
               a.y * sW[(k + 1) * 128 + 64 + lane] +
               a.z * sW[(k + 2) * 128 + 64 + lane] +
               a.w * sW[(k + 3) * 128 + 64 + lane];
    }
    if (valid) {
      t_out[(size_t)node * HH + lane] = f2bf(acc_t);
      r_out[(size_t)node * HH + lane] = acc_r;
    }
    __syncthreads();
  }
}

// h[n] = sigmoid(mean(t[nbrs(n)]) + r[n]); t bf16 rows, r/h f32 rows.
// One wave per node; 32 lanes per row (u32 = 2 bf16 per lane), 2 rows in
// flight per half via manual unroll; no LDS, no shuffle broadcasts.
__global__ __launch_bounds__(256) void agg_sig(
    const unsigned short* __restrict__ t, const float* __restrict__ r,
    const int* __restrict__ rp, const int* __restrict__ csr,
    float* __restrict__ h, int n_nodes) {
  int wv = threadIdx.x >> 6, lane = threadIdx.x & 63;
  int node = blockIdx.x * 4 + wv;
  if (node >= n_nodes) return;
  int rs = rp[node], re = rp[node + 1];
  int deg = re - rs;
  int half = lane >> 5, col = lane & 31;

  float alo = 0.0f, ahi = 0.0f;
  int j = rs + half;
  for (; j + 2 < re; j += 4) {
    int i0 = csr[j];
    int i1 = csr[j + 2];
    unsigned u0 = ((const unsigned*)(t + (size_t)i0 * HH))[col];
    unsigned u1 = ((const unsigned*)(t + (size_t)i1 * HH))[col];
    alo += bflo(u0) + bflo(u1);
    ahi += bfhi(u0) + bfhi(u1);
  }
  for (; j < re; j += 2) {
    int i0 = csr[j];
    unsigned u0 = ((const unsigned*)(t + (size_t)i0 * HH))[col];
    alo += bflo(u0);
    ahi += bfhi(u0);
  }
  alo += __shfl_xor(alo, 32);
  ahi += __shfl_xor(ahi, 32);

  if (lane < 32) {
    float inv = 1.0f / fmaxf((float)deg, 1.0f);
    float2 rv = ((const float2*)(r + (size_t)node * HH))[col];
    float2 o;
    o.x = sigmoidf_(alo * inv + rv.x);
    o.y = sigmoidf_(ahi * inv + rv.y);
    ((float2*)(h + (size_t)node * HH))[col] = o;
  }
}

// h3 = sigmoid(h2 @ Wlin1 + blin1); out = softmax(h3 @ Wlin2 + blin2)
__global__ __launch_bounds__(512, 8) void head_k(
    const float* __restrict__ h2,
    const float* __restrict__ Wlin1, const float* __restrict__ blin1,
    const float* __restrict__ Wlin2, const float* __restrict__ blin2,
    float* __restrict__ out, int n_nodes) {
  __shared__ float sWl1[HH * HH];
  __shared__ float sWl2[HH * 2];
  __shared__ float sbl1[HH], sbl2[2];
  __shared__ float sh2[8][HH];
  for (int i = threadIdx.x; i < HH * HH; i += 512) sWl1[i] = Wlin1[i];
  if (threadIdx.x < HH * 2) sWl2[threadIdx.x] = Wlin2[threadIdx.x];
  if (threadIdx.x < HH) sbl1[threadIdx.x] = blin1[threadIdx.x];
  if (threadIdx.x < 2) sbl2[threadIdx.x] = blin2[threadIdx.x];
  __syncthreads();

  int wv = threadIdx.x >> 6, lane = threadIdx.x & 63;
  for (int nbase = blockIdx.x * 8; nbase < n_nodes; nbase += gridDim.x * 8) {
    int node = nbase + wv;
    bool valid = node < n_nodes;
    int nn = valid ? node : (n_nodes - 1);
    sh2[wv][lane] = h2[(size_t)nn * HH + lane];
    __syncthreads();

    float acc3 = sbl1[lane];
#pragma unroll
    for (int k = 0; k < HH; k++) acc3 += sh2[wv][k] * sWl1[k * HH + lane];
    float h3 = sigmoidf_(acc3);

    float l0 = h3 * sWl2[lane * 2 + 0];
    float l1 = h3 * sWl2[lane * 2 + 1];
    for (int off = 32; off > 0; off >>= 1) {
      l0 += __shfl_xor(l0, off);
      l1 += __shfl_xor(l1, off);
    }
    if (valid && lane == 0) {
      l0 += sbl2[0];
      l1 += sbl2[1];
      float m = fmaxf(l0, l1);
      float p0 = __expf(l0 - m), p1 = __expf(l1 - m);
      float s = 1.0f / (p0 + p1);
      out[(size_t)node * 2 + 0] = p0 * s;
      out[(size_t)node * 2 + 1] = p1 * s;
    }
    __syncthreads();
  }
}

extern "C" void kernel_launch(void* const* d_in, const int* in_sizes, int n_in,
                              void* d_out, int out_size, void* d_ws, size_t ws_size,
                              hipStream_t stream) {
  const float* x     = (const float*)d_in[0];
  const int*   ei    = (const int*)d_in[1];
  const float* W1l   = (const float*)d_in[2];
  const float* b1l   = (const float*)d_in[3];
  const float* W1r   = (const float*)d_in[4];
  const float* W2l   = (const float*)d_in[5];
  const float* b2l   = (const float*)d_in[6];
  const float* W2r   = (const float*)d_in[7];
  const float* Wlin1 = (const float*)d_in[8];
  const float* blin1 = (const float*)d_in[9];
  const float* Wlin2 = (const float*)d_in[10];
  const float* blin2 = (const float*)d_in[11];
  float* out = (float*)d_out;

  int n = in_sizes[0] / NF1;
  int E = in_sizes[1] / 2;
  int nb = (n + 255) / 256;

  int* rp     = (int*)d_ws;                 // [n+1]
  int* cursor = rp + (n + 1);               // [n]
  int* bsum   = cursor + n;                 // [nb]
  int* csr    = bsum + nb;                  // [E]
  size_t off = (size_t)(n + 1 + n + nb + E) * sizeof(int);
  off = (off + 255) & ~(size_t)255;
  unsigned short* tbuf = (unsigned short*)((char*)d_ws + off);  // [n,64] bf16
  off += (size_t)n * HH * sizeof(unsigned short);
  off = (off + 255) & ~(size_t)255;
  float* rbuf = (float*)((char*)d_ws + off);  // [n,64] f32
  off += (size_t)n * HH * sizeof(float);
  off = (off + 255) & ~(size_t)255;
  float* hbuf = (float*)((char*)d_ws + off);  // [n,64] f32 (h1, then h2)

  hipMemsetAsync(rp, 0, (size_t)(n + 1) * sizeof(int), stream);

  int eb = (E + 255) / 256;
  k_hist<<<eb, 256, 0, stream>>>(ei, rp, E);
  k_scan1<<<nb, 256, 0, stream>>>(rp, bsum, n);
  k_scan2<<<1, 512, 0, stream>>>(bsum, nb);
  k_scan3<<<nb, 256, 0, stream>>>(rp, cursor, bsum, n, E);
  k_scatter<<<eb, 256, 0, stream>>>(ei, cursor, csr, E);

  int gemmb = (n + 7) / 8;
  if (gemmb > 2048) gemmb = 2048;
  int aggb = (n + 3) / 4;

  // layer 1: t = x@W1l (bf16), r = x@W1r + b1l; h1 = sigmoid(mean(t)+r)
  gemm_tr<NF1><<<gemmb, 512, 0, stream>>>(x, W1l, W1r, b1l, tbuf, rbuf, n);
  agg_sig<<<aggb, 256, 0, stream>>>(tbuf, rbuf, rp, csr, hbuf, n);

  // layer 2: t = h1@W2l (bf16), r = h1@W2r + b2l; h2 = sigmoid(mean(t)+r)
  gemm_tr<HH><<<gemmb, 512, 0, stream>>>(hbuf, W2l, W2r, b2l, tbuf, rbuf, n);
  agg_sig<<<aggb, 256, 0, stream>>>(tbuf, rbuf, rp, csr, hbuf, n);

  head_k<<<gemmb, 512, 0, stream>>>(hbuf, Wlin1, blin1, Wlin2, blin2, out, n);
}

// Round 7
// 352.963 us; speedup vs baseline: 1.4095x; 1.4095x over previous
//
#include <hip/hip_runtime.h>
#include <math.h>

// GraphSAGE 2-layer + MLP head + softmax(2).
// CSR via bucketed counting sort with per-bucket private bins regions:
//   bin_edges: LDS-ranked binning into per-bucket regions bins[b*BCAP..]
//   scan_buckets: 196-entry exclusive scan of counts -> global CSR bases
//   build_csr: per-bucket block builds rp + csr in an L2-hot window
// Then per layer {GEMM (t=X@Wl bf16, r=X@Wr+b f32), AGG (sigmoid(mean+r))},
// then MLP head. Uses mean linearity: mean(X[nbrs])@Wl == mean((X@Wl)[nbrs]).

#define NF1 48
#define HH 64
#define BKT_SHIFT 9
#define BKT_SZ (1 << BKT_SHIFT)
#define BCAP 9216  // per-bucket bins capacity; mean ~8192, std ~90 -> +11 sigma
#define EPB 16     // edges per thread in bin_edges

__device__ __forceinline__ float sigmoidf_(float v) {
  return 1.0f / (1.0f + __expf(-v));
}
__device__ __forceinline__ float bflo(unsigned w) {
  union { unsigned u; float f; } c; c.u = w << 16; return c.f;
}
__device__ __forceinline__ float bfhi(unsigned w) {
  union { unsigned u; float f; } c; c.u = w & 0xffff0000u; return c.f;
}
__device__ __forceinline__ unsigned short f2bf(float f) {
  union { float f; unsigned u; } c; c.f = f;
  unsigned r = c.u + 0x7fffu + ((c.u >> 16) & 1u);  // RNE
  return (unsigned short)(r >> 16);
}

// Phase A: bin edges into per-bucket regions. bins[b*BCAP + pos] = (dl<<23|src).
__global__ __launch_bounds__(256) void bin_edges(
    const int* __restrict__ ei, int* __restrict__ cursor,
    unsigned* __restrict__ bins, int E, int NB) {
  __shared__ int hist[256];
  __shared__ int gbase[256];
  for (int i = threadIdx.x; i < NB; i += 256) hist[i] = 0;
  __syncthreads();
  int base_e = blockIdx.x * (256 * EPB) + threadIdx.x;
  unsigned pk[EPB];
  int bk[EPB], rk[EPB];
#pragma unroll
  for (int k = 0; k < EPB; k++) {
    int e = base_e + k * 256;
    bk[k] = -1;
    if (e < E) {
      int s = ei[e], d = ei[E + e];
      int b = d >> BKT_SHIFT;
      pk[k] = ((unsigned)(d & (BKT_SZ - 1)) << 23) | (unsigned)s;
      bk[k] = b;
      rk[k] = atomicAdd(&hist[b], 1);  // LDS atomic -> rank in (block,bucket)
    }
  }
  __syncthreads();
  for (int i = threadIdx.x; i < NB; i += 256) {
    int c = hist[i];
    gbase[i] = (c > 0) ? atomicAdd(&cursor[i], c) : 0;  // offset within bucket
  }
  __syncthreads();
#pragma unroll
  for (int k = 0; k < EPB; k++) {
    if (bk[k] >= 0) {
      int pos = gbase[bk[k]] + rk[k];
      bins[(size_t)bk[k] * BCAP + pos] = pk[k];
    }
  }
}

// Phase A2: exclusive scan of bucket counts (NB <= 256), base[NB] = E.
__global__ __launch_bounds__(256) void scan_buckets(
    const int* __restrict__ cursor, int* __restrict__ base, int NB) {
  __shared__ int a[256], b[256];
  int tid = threadIdx.x;
  int v = (tid < NB) ? cursor[tid] : 0;
  a[tid] = v;
  __syncthreads();
  int* s = a;
  int* d = b;
  for (int off = 1; off < 256; off <<= 1) {
    int t = s[tid] + ((tid >= off) ? s[tid - off] : 0);
    d[tid] = t;
    __syncthreads();
    int* tmp = s; s = d; d = tmp;
  }
  if (tid < NB) base[tid] = s[tid] - v;
  if (tid == NB - 1) base[NB] = s[tid];
}

// Phase B: one block per bucket. Local hist -> scan -> rp (coalesced) and
// csr scatter within the bucket's contiguous (L2-hot) window.
__global__ __launch_bounds__(512) void build_csr(
    const unsigned* __restrict__ bins, const int* __restrict__ cursor,
    const int* __restrict__ base,
    int* __restrict__ rp, int* __restrict__ csr, int n_nodes, int E, int NB) {
  __shared__ int hist[BKT_SZ];
  __shared__ int aa[BKT_SZ], bb[BKT_SZ];
  __shared__ int cur[BKT_SZ];
  int b = blockIdx.x;
  int tid = threadIdx.x;
  int node0 = b << BKT_SHIFT;
  int gb = base[b];
  int cnt = cursor[b];
  const unsigned* bp = bins + (size_t)b * BCAP;
  hist[tid] = 0;
  __syncthreads();
  for (int i = tid; i < cnt; i += 512) {
    atomicAdd(&hist[bp[i] >> 23], 1);
  }
  __syncthreads();
  int v = hist[tid];
  aa[tid] = v;
  __syncthreads();
  int* s = aa;
  int* d = bb;
  for (int off = 1; off < BKT_SZ; off <<= 1) {
    int t = s[tid] + ((tid >= off) ? s[tid - off] : 0);
    d[tid] = t;
    __syncthreads();
    int* tmp = s; s = d; d = tmp;
  }
  int loc = s[tid] - v;  // exclusive
  int node = node0 + tid;
  if (node < n_nodes) rp[node] = gb + loc;
  if (b == NB - 1 && tid == 0) rp[n_nodes] = E;
  cur[tid] = gb + loc;
  __syncthreads();
  for (int i = tid; i < cnt; i += 512) {
    unsigned p = bp[i];
    int dl = (int)(p >> 23);
    int pos = atomicAdd(&cur[dl], 1);
    csr[pos] = (int)(p & 0x7FFFFFu);
  }
}

// t_out[n] = X[n] @ Wl  (bf16), r_out[n] = X[n] @ Wr + bias  (f32)
template <int K>
__global__ __launch_bounds__(512) void gemm_tr(
    const float* __restrict__ X, const float* __restrict__ Wl,
    const float* __restrict__ Wr, const float* __restrict__ bias,
    unsigned short* __restrict__ t_out, float* __restrict__ r_out,
    int n_nodes) {
  __shared__ float sW[K * 128];  // [k][j]: j<64 -> Wl, j>=64 -> Wr
  __shared__ float sb[64];
  __shared__ float sx[8][K];
  for (int i = threadIdx.x; i < K * 64; i += 512) {
    int k = i >> 6, j = i & 63;
    sW[k * 128 + j] = Wl[i];
    sW[k * 128 + 64 + j] = Wr[i];
  }
  if (threadIdx.x < 64) sb[threadIdx.x] = bias[threadIdx.x];
  __syncthreads();

  int wv = threadIdx.x >> 6, lane = threadIdx.x & 63;
  for (int nbase = blockIdx.x * 8; nbase < n_nodes; nbase += gridDim.x * 8) {
    int node = nbase + wv;
    bool valid = node < n_nodes;
    int nn = valid ? node : (n_nodes - 1);
    if (lane < K) sx[wv][lane] = X[(size_t)nn * K + lane];
    __syncthreads();

    float acc_t = 0.0f, acc_r = sb[lane];
#pragma unroll
    for (int k = 0; k < K; k += 4) {
      float4 a = *(const float4*)&sx[wv][k];
      acc_t += a.x * sW[(k + 0) * 128 + lane] + a.y * sW[(k + 1) * 128 + lane] +
               a.z * sW[(k + 2) * 128 + lane] + a.w * sW[(k + 3) * 128 + lane];
      acc_r += a.x * sW[(k + 0) * 128 + 64 + lane] +
               a.y * sW[(k + 1) * 128 + 64 + lane] +
               a.z * sW[(k + 2) * 128 + 64 + lane] +
               a.w * sW[(k + 3) * 128 + 64 + lane];
    }
    if (valid) {
      t_out[(size_t)node * HH + lane] = f2bf(acc_t);
      r_out[(size_t)node * HH + lane] = acc_r;
    }
    __syncthreads();
  }
}

// h[n] = sigmoid(mean(t[nbrs(n)]) + r[n]); t bf16 rows, r/h f32 rows.
__global__ __launch_bounds__(256) void agg_sig(
    const unsigned short* __restrict__ t, const float* __restrict__ r,
    const int* __restrict__ rp, const int* __restrict__ csr,
    float* __restrict__ h, int n_nodes) {
  int wv = threadIdx.x >> 6, lane = threadIdx.x & 63;
  int node = blockIdx.x * 4 + wv;
  if (node >= n_nodes) return;
  int rs = rp[node], re = rp[node + 1];
  int deg = re - rs;
  int half = lane >> 5, col = lane & 31;

  float alo = 0.0f, ahi = 0.0f;
  int j = rs + half;
  for (; j + 2 < re; j += 4) {
    int i0 = csr[j];
    int i1 = csr[j + 2];
    unsigned u0 = ((const unsigned*)(t + (size_t)i0 * HH))[col];
    unsigned u1 = ((const unsigned*)(t + (size_t)i1 * HH))[col];
    alo += bflo(u0) + bflo(u1);
    ahi += bfhi(u0) + bfhi(u1);
  }
  for (; j < re; j += 2) {
    int i0 = csr[j];
    unsigned u0 = ((const unsigned*)(t + (size_t)i0 * HH))[col];
    alo += bflo(u0);
    ahi += bfhi(u0);
  }
  alo += __shfl_xor(alo, 32);
  ahi += __shfl_xor(ahi, 32);

  if (lane < 32) {
    float inv = 1.0f / fmaxf((float)deg, 1.0f);
    float2 rv = ((const float2*)(r + (size_t)node * HH))[col];
    float2 o;
    o.x = sigmoidf_(alo * inv + rv.x);
    o.y = sigmoidf_(ahi * inv + rv.y);
    ((float2*)(h + (size_t)node * HH))[col] = o;
  }
}

// h3 = sigmoid(h2 @ Wlin1 + blin1); out = softmax(h3 @ Wlin2 + blin2)
__global__ __launch_bounds__(512, 8) void head_k(
    const float* __restrict__ h2,
    const float* __restrict__ Wlin1, const float* __restrict__ blin1,
    const float* __restrict__ Wlin2, const float* __restrict__ blin2,
    float* __restrict__ out, int n_nodes) {
  __shared__ float sWl1[HH * HH];
  __shared__ float sWl2[HH * 2];
  __shared__ float sbl1[HH], sbl2[2];
  __shared__ float sh2[8][HH];
  for (int i = threadIdx.x; i < HH * HH; i += 512) sWl1[i] = Wlin1[i];
  if (threadIdx.x < HH * 2) sWl2[threadIdx.x] = Wlin2[threadIdx.x];
  if (threadIdx.x < HH) sbl1[threadIdx.x] = blin1[threadIdx.x];
  if (threadIdx.x < 2) sbl2[threadIdx.x] = blin2[threadIdx.x];
  __syncthreads();

  int wv = threadIdx.x >> 6, lane = threadIdx.x & 63;
  for (int nbase = blockIdx.x * 8; nbase < n_nodes; nbase += gridDim.x * 8) {
    int node = nbase + wv;
    bool valid = node < n_nodes;
    int nn = valid ? node : (n_nodes - 1);
    sh2[wv][lane] = h2[(size_t)nn * HH + lane];
    __syncthreads();

    float acc3 = sbl1[lane];
#pragma unroll
    for (int k = 0; k < HH; k++) acc3 += sh2[wv][k] * sWl1[k * HH + lane];
    float h3 = sigmoidf_(acc3);

    float l0 = h3 * sWl2[lane * 2 + 0];
    float l1 = h3 * sWl2[lane * 2 + 1];
    for (int off = 32; off > 0; off >>= 1) {
      l0 += __shfl_xor(l0, off);
      l1 += __shfl_xor(l1, off);
    }
    if (valid && lane == 0) {
      l0 += sbl2[0];
      l1 += sbl2[1];
      float m = fmaxf(l0, l1);
      float p0 = __expf(l0 - m), p1 = __expf(l1 - m);
      float s = 1.0f / (p0 + p1);
      out[(size_t)node * 2 + 0] = p0 * s;
      out[(size_t)node * 2 + 1] = p1 * s;
    }
    __syncthreads();
  }
}

extern "C" void kernel_launch(void* const* d_in, const int* in_sizes, int n_in,
                              void* d_out, int out_size, void* d_ws, size_t ws_size,
                              hipStream_t stream) {
  const float* x     = (const float*)d_in[0];
  const int*   ei    = (const int*)d_in[1];
  const float* W1l   = (const float*)d_in[2];
  const float* b1l   = (const float*)d_in[3];
  const float* W1r   = (const float*)d_in[4];
  const float* W2l   = (const float*)d_in[5];
  const float* b2l   = (const float*)d_in[6];
  const float* W2r   = (const float*)d_in[7];
  const float* Wlin1 = (const float*)d_in[8];
  const float* blin1 = (const float*)d_in[9];
  const float* Wlin2 = (const float*)d_in[10];
  const float* blin2 = (const float*)d_in[11];
  float* out = (float*)d_out;

  int n = in_sizes[0] / NF1;
  int E = in_sizes[1] / 2;
  int NB = (n + BKT_SZ - 1) >> BKT_SHIFT;  // 196 for this problem (<= 256)

  int* base   = (int*)d_ws;                 // [NB+1]
  int* cursor = base + NB + 1;              // [NB]
  int* rp     = cursor + NB;                // [n+1]
  int* csr    = rp + n + 1;                 // [E]
  size_t off = (size_t)(NB + 1 + NB + n + 1 + E) * sizeof(int);
  off = (off + 255) & ~(size_t)255;
  unsigned* bins = (unsigned*)((char*)d_ws + off);  // [NB*BCAP] u32 (dead after CSR)
  // tbuf aliases bins: n*64*2 = 12.8MB >= NB*BCAP*4 = 7.2MB, used only after build
  unsigned short* tbuf = (unsigned short*)bins;     // [n,64] bf16
  size_t reg = (size_t)NB * BCAP * sizeof(unsigned);
  size_t treg = (size_t)n * HH * sizeof(unsigned short);
  off += (reg > treg ? reg : treg);
  off = (off + 255) & ~(size_t)255;
  float* rbuf = (float*)((char*)d_ws + off);  // [n,64] f32
  off += (size_t)n * HH * sizeof(float);
  off = (off + 255) & ~(size_t)255;
  float* hbuf = (float*)((char*)d_ws + off);  // [n,64] f32 (h1, then h2)

  hipMemsetAsync(cursor, 0, (size_t)NB * sizeof(int), stream);

  int abk = (E + 256 * EPB - 1) / (256 * EPB);
  bin_edges<<<abk, 256, 0, stream>>>(ei, cursor, bins, E, NB);
  scan_buckets<<<1, 256, 0, stream>>>(cursor, base, NB);
  build_csr<<<NB, 512, 0, stream>>>(bins, cursor, base, rp, csr, n, E, NB);

  int gemmb = (n + 7) / 8;
  if (gemmb > 2048) gemmb = 2048;
  int aggb = (n + 3) / 4;

  // layer 1: t = x@W1l (bf16), r = x@W1r + b1l; h1 = sigmoid(mean(t)+r)
  gemm_tr<NF1><<<gemmb, 512, 0, stream>>>(x, W1l, W1r, b1l, tbuf, rbuf, n);
  agg_sig<<<aggb, 256, 0, stream>>>(tbuf, rbuf, rp, csr, hbuf, n);

  // layer 2: t = h1@W2l (bf16), r = h1@W2r + b2l; h2 = sigmoid(mean(t)+r)
  gemm_tr<HH><<<gemmb, 512, 0, stream>>>(hbuf, W2l, W2r, b2l, tbuf, rbuf, n);
  agg_sig<<<aggb, 256, 0, stream>>>(tbuf, rbuf, rp, csr, hbuf, n);

  head_k<<<gemmb, 512, 0, stream>>>(hbuf, Wlin1, blin1, Wlin2, blin2, out, n);
}